// Round 10
// baseline (214.845 us; speedup 1.0000x reference)
//
#include <hip/hip_runtime.h>
#include <stdint.h>

#define H 18
#define TPB 256
#define RPB 128  // races per block: 2 lanes per race

// R10: 2 lanes per race. Per-thread state halves to 9-element arrays
// (live set ~30 values -> real registers, no compiler serialization),
// waves double (latency hiding), LDS ~12KB -> occupancy cap 100%.
// No max-shift: scores clamped to [-10,10] so exp(s) is f32-safe.
__global__ __launch_bounds__(TPB) void pl_main(const float* __restrict__ scores,
                                               const int* __restrict__ rankings,
                                               const unsigned char* __restrict__ mask8,
                                               int B,
                                               float* __restrict__ partial_loss,
                                               int* __restrict__ partial_cnt) {
    __shared__ float sS[RPB * H];            // 9.2 KB clamped scores
    __shared__ unsigned char sK8[RPB * H];   // 2.3 KB keys (valid ? rank : 31)
    __shared__ int sFlag;
    __shared__ float ls[TPB / 64];
    __shared__ int   cs[TPB / 64];

    const int t = threadIdx.x;
    const int lane = t & 63;
    const int wid = t >> 6;

    // ---- mask dtype detect (proven R4-R9): int32 bools -> words 0/1;
    // u8-packed bools -> word >1 within 256 words w.p. ~1. L2-hot.
    if (t == 0) sFlag = 0;
    __syncthreads();
    {
        unsigned int w = reinterpret_cast<const unsigned int*>(mask8)[t];
        if (__any(w > 1u) && lane == 0) atomicOr(&sFlag, 1);
    }
    __syncthreads();
    const bool u8mode = (sFlag != 0);

    const int race0 = blockIdx.x * RPB;
    const int limit = min(RPB, B - race0);
    const int nflat2 = limit * 9;  // float2 elements to stage

    const float2* g_s2 = reinterpret_cast<const float2*>(scores) + (size_t)race0 * 9;
    const int2*   g_r2 = reinterpret_cast<const int2*>(rankings) + (size_t)race0 * 9;

    // ---- coalesced staging (1152 float2 / 256 threads = 5 steps);
    // clamp + key computation fused here, read each input exactly once.
#pragma unroll
    for (int k = 0; k < 5; ++k) {
        int f2 = k * TPB + t;
        if (f2 < nflat2) {
            float2 sv = g_s2[f2];
            int2   rv = g_r2[f2];
            int m0, m1;
            if (u8mode) {
                uchar2 mb = *reinterpret_cast<const uchar2*>(
                    mask8 + (size_t)race0 * 18 + 2 * (size_t)f2);
                m0 = mb.x; m1 = mb.y;
            } else {
                int2 mb = reinterpret_cast<const int2*>(mask8)[(size_t)race0 * 9 + f2];
                m0 = mb.x; m1 = mb.y;
            }
            float s0 = fminf(fmaxf(sv.x, -10.0f), 10.0f);
            float s1 = fminf(fmaxf(sv.y, -10.0f), 10.0f);
            reinterpret_cast<float2*>(sS)[f2] = make_float2(s0, s1);
            unsigned int k0 = (m0 != 0 && rv.x >= 0) ? (unsigned int)min(rv.x, 30) : 31u;
            unsigned int k1 = (m1 != 0 && rv.y >= 0) ? (unsigned int)min(rv.y, 30) : 31u;
            reinterpret_cast<unsigned short*>(sK8)[f2] = (unsigned short)(k0 | (k1 << 8));
        }
    }
    __syncthreads();

    const int rb  = t >> 1;         // race within block
    const int sub = t & 1;          // which 9-horse half
    const bool live = rb < limit;

    // ---- my 9 horses into registers (static indices only)
    float s[9], e[9], run[9];
    int ck[9];
    int nloc = 0;
#pragma unroll
    for (int i = 0; i < 9; ++i) {
        int j = sub * 9 + i;
        float sv = sS[rb * H + j];
        int kk = live ? (int)sK8[rb * H + j] : 31;
        bool v = kk < 31;
        s[i] = sv;
        ck[i] = (kk << 5) | j;      // lexicographic (rank, idx), all distinct
        e[i] = v ? __expf(sv) : 0.0f;
        nloc += v ? 1 : 0;
    }

    // ---- run_i = sum over all 18 horses b with ck_b >= ck_i of e_b
    // local half: 36 symmetric pairs
#pragma unroll
    for (int i = 0; i < 9; ++i) run[i] = e[i];
#pragma unroll
    for (int a = 0; a < 9; ++a) {
#pragma unroll
        for (int b = a + 1; b < 9; ++b) {
            bool cc = ck[b] > ck[a];
            run[a] += cc ? e[b] : 0.0f;
            run[b] += cc ? 0.0f : e[a];
        }
    }
    // cross half: stream partner lane's 9 via shfl_xor(1)
#pragma unroll
    for (int p = 0; p < 9; ++p) {
        float pe = __shfl_xor(e[p], 1);
        int  pck = __shfl_xor(ck[p], 1);
#pragma unroll
        for (int i = 0; i < 9; ++i) {
            run[i] += (pck > ck[i]) ? pe : 0.0f;
        }
    }

    // ---- terms; track last pick (max ck among valid); branchless
    float loss = 0.0f, last = 0.0f;
    int best = -1;
#pragma unroll
    for (int i = 0; i < 9; ++i) {
        float term = __logf(run[i]) - s[i];
        term = fminf(fmaxf(term, 1.0000000e-8f), 18.420680744f);
        bool v = ck[i] < (31 << 5);
        loss += v ? term : 0.0f;
        int c = v ? ck[i] : -1;
        bool up = c > best;
        best = up ? c : best;
        last = up ? term : last;
    }

    // ---- combine the two lanes of this race
    loss += __shfl_xor(loss, 1);
    int n = nloc + __shfl_xor(nloc, 1);
    int pbest = __shfl_xor(best, 1);
    float plast = __shfl_xor(last, 1);
    last = (pbest > best) ? plast : last;
    float th_loss = (n >= 2 && sub == 0) ? (loss - last) : 0.0f;
    int th_cnt = (n >= 2 && sub == 0) ? 1 : 0;

    // ---- block reduce
#pragma unroll
    for (int off = 32; off >= 1; off >>= 1) {
        th_loss += __shfl_down(th_loss, off);
        th_cnt  += __shfl_down(th_cnt, off);
    }
    if (lane == 0) { ls[wid] = th_loss; cs[wid] = th_cnt; }
    __syncthreads();
    if (t == 0) {
        float L = 0.0f; int C = 0;
#pragma unroll
        for (int w = 0; w < TPB / 64; ++w) { L += ls[w]; C += cs[w]; }
        partial_loss[blockIdx.x] = L;
        partial_cnt[blockIdx.x]  = C;
    }
}

__global__ __launch_bounds__(1024) void pl_final(const float* __restrict__ partial_loss,
                                                 const int* __restrict__ partial_cnt,
                                                 int nb, float* __restrict__ out) {
    float L = 0.0f;
    int C = 0;
    for (int i = threadIdx.x; i < nb; i += 1024) {
        L += partial_loss[i];
        C += partial_cnt[i];
    }
#pragma unroll
    for (int off = 32; off >= 1; off >>= 1) {
        L += __shfl_down(L, off);
        C += __shfl_down(C, off);
    }
    __shared__ float ls[1024 / 64];
    __shared__ int   cs[1024 / 64];
    int wid = threadIdx.x >> 6;
    int lane = threadIdx.x & 63;
    if (lane == 0) { ls[wid] = L; cs[wid] = C; }
    __syncthreads();
    if (threadIdx.x == 0) {
        float tl = 0.0f;
        int tc = 0;
#pragma unroll
        for (int w = 0; w < 1024 / 64; ++w) { tl += ls[w]; tc += cs[w]; }
        out[0] = (tc > 0) ? (tl / (float)tc) : 0.0f;
    }
}

extern "C" void kernel_launch(void* const* d_in, const int* in_sizes, int n_in,
                              void* d_out, int out_size, void* d_ws, size_t ws_size,
                              hipStream_t stream) {
    const float*         scores   = (const float*)d_in[0];
    const int*           rankings = (const int*)d_in[1];
    const unsigned char* mask     = (const unsigned char*)d_in[2];

    int B = in_sizes[0] / H;
    int nb = (B + RPB - 1) / RPB;  // 7813 blocks for B=1e6

    float* pl = (float*)d_ws;
    int*   pc = (int*)((char*)d_ws + (((size_t)nb * sizeof(float) + 255) & ~(size_t)255));

    pl_main<<<nb, TPB, 0, stream>>>(scores, rankings, mask, B, pl, pc);
    pl_final<<<1, 1024, 0, stream>>>(pl, pc, nb, (float*)d_out);
}

// Round 11
// 213.906 us; speedup vs baseline: 1.0044x; 1.0044x over previous
//
#include <hip/hip_runtime.h>
#include <stdint.h>

#define H 18
#define TPB 256
#define RPB 128  // races per block: 2 lanes per race

// R11: staging = full elementwise transform (float4/int4 16B loads, clamp,
// valid, exp) -> LDS holds only e (f32) and ck=(key<<5)|idx (u16).
// Compute = 36 local + 81 cross register pair-ops + log(run/e) terms.
// No s[], no exp, no clamps in the compute phase.
__global__ __launch_bounds__(TPB) void pl_main(const float* __restrict__ scores,
                                               const int* __restrict__ rankings,
                                               const unsigned char* __restrict__ mask8,
                                               int B,
                                               float* __restrict__ partial_loss,
                                               int* __restrict__ partial_cnt) {
    __shared__ float sE[RPB * H];            // 9 KB: e = valid ? exp(clamp(s)) : 0
    __shared__ unsigned short sCk[RPB * H];  // 4.5 KB: ck
    __shared__ int sFlag;
    __shared__ float ls[TPB / 64];
    __shared__ int   cs[TPB / 64];

    const int t = threadIdx.x;
    const int lane = t & 63;
    const int wid = t >> 6;

    // ---- mask dtype detect (proven R4-R10): int32 bools -> words 0/1;
    // u8-packed bools -> word >1 within 256 words w.p. ~1. L2-hot.
    if (t == 0) sFlag = 0;
    __syncthreads();
    {
        unsigned int w = reinterpret_cast<const unsigned int*>(mask8)[t];
        if (__any(w > 1u) && lane == 0) atomicOr(&sFlag, 1);
    }
    __syncthreads();
    const bool u8mode = (sFlag != 0);

    const int race0 = blockIdx.x * RPB;
    const int limit = min(RPB, B - race0);
    const int nelem = limit * H;
    const int nf4 = nelem >> 2;              // full 4-element chunks

    const float4* g_s4 = reinterpret_cast<const float4*>(scores + (size_t)race0 * H);
    const int4*   g_r4 = reinterpret_cast<const int4*>(rankings + (size_t)race0 * H);
    const int4*   g_m4 = reinterpret_cast<const int4*>(mask8) + ((size_t)race0 * H >> 2);
    const uchar4* g_mu4 = reinterpret_cast<const uchar4*>(mask8 + (size_t)race0 * H);

    for (int f4 = t; f4 < nf4; f4 += TPB) {
        float4 sv = g_s4[f4];
        int4   rv = g_r4[f4];
        int m0, m1, m2, m3;
        if (u8mode) {
            uchar4 mb = g_mu4[f4];
            m0 = mb.x; m1 = mb.y; m2 = mb.z; m3 = mb.w;
        } else {
            int4 mb = g_m4[f4];
            m0 = mb.x; m1 = mb.y; m2 = mb.z; m3 = mb.w;
        }
        int lf = f4 * 4;
        int r  = lf / 18;                 // compiler magic-mul
        int j0 = lf - r * 18;             // horse idx of elem 0; j0+3 wraps at most once

        float sc[4] = {sv.x, sv.y, sv.z, sv.w};
        int   rk[4] = {rv.x, rv.y, rv.z, rv.w};
        int   mk[4] = {m0, m1, m2, m3};
        unsigned int ckp[4];
        float ev[4];
#pragma unroll
        for (int c = 0; c < 4; ++c) {
            int j = j0 + c;
            j = (j >= 18) ? (j - 18) : j;
            bool v = (mk[c] != 0) && (rk[c] >= 0);
            unsigned int key = v ? (unsigned int)min(rk[c], 30) : 31u;
            ckp[c] = (key << 5) | (unsigned int)j;
            float scl = fminf(fmaxf(sc[c], -10.0f), 10.0f);
            ev[c] = v ? __expf(scl) : 0.0f;
        }
        reinterpret_cast<float4*>(sE)[f4] =
            make_float4(ev[0], ev[1], ev[2], ev[3]);
        uint2 pk;
        pk.x = ckp[0] | (ckp[1] << 16);
        pk.y = ckp[2] | (ckp[3] << 16);
        reinterpret_cast<uint2*>(sCk)[f4] = pk;
    }
    // element tail (only when limit*18 % 4 != 0; at most 2 elements)
    for (int idx = nf4 * 4 + t; idx < nelem; idx += TPB) {
        float sc = scores[(size_t)race0 * H + idx];
        int   rk = rankings[(size_t)race0 * H + idx];
        int   mk = u8mode ? (int)mask8[(size_t)race0 * H + idx]
                          : reinterpret_cast<const int*>(mask8)[(size_t)race0 * H + idx];
        int r  = idx / 18;
        int j  = idx - r * 18;
        bool v = (mk != 0) && (rk >= 0);
        unsigned int key = v ? (unsigned int)min(rk, 30) : 31u;
        sCk[idx] = (unsigned short)((key << 5) | (unsigned int)j);
        float scl = fminf(fmaxf(sc, -10.0f), 10.0f);
        sE[idx] = v ? __expf(scl) : 0.0f;
    }
    __syncthreads();

    const int rb  = t >> 1;        // race within block (lane pair 2t,2t+1)
    const int sub = t & 1;         // which 9-horse half
    const bool live = rb < limit;

    // ---- my 9 horses: e and ck only
    float e[9], run[9];
    int ck[9];
    int nloc = 0;
#pragma unroll
    for (int i = 0; i < 9; ++i) {
        int j = sub * 9 + i;
        e[i]  = sE[rb * H + j];
        ck[i] = (int)sCk[rb * H + j];
        nloc += (ck[i] < (31 << 5)) ? 1 : 0;
    }
    nloc = live ? nloc : 0;

    // ---- run_i = sum over all 18 b with ck_b >= ck_i of e_b
#pragma unroll
    for (int i = 0; i < 9; ++i) run[i] = e[i];
#pragma unroll
    for (int a = 0; a < 9; ++a) {
#pragma unroll
        for (int b = a + 1; b < 9; ++b) {
            bool cc = ck[b] > ck[a];
            run[a] += cc ? e[b] : 0.0f;
            run[b] += cc ? 0.0f : e[a];
        }
    }
#pragma unroll
    for (int p = 0; p < 9; ++p) {
        float pe = __shfl_xor(e[p], 1);
        int  pck = __shfl_xor(ck[p], 1);
#pragma unroll
        for (int i = 0; i < 9; ++i) {
            run[i] += (pck > ck[i]) ? pe : 0.0f;
        }
    }

    // ---- terms: log(run/e) == log(run) - s  (e = exp(s) exactly).
    // invalid: e=0 -> inf/NaN -> clamps produce finite -> selected out.
    float loss = 0.0f, last = 0.0f;
    int best = -1;
#pragma unroll
    for (int i = 0; i < 9; ++i) {
        float term = __logf(__fdividef(run[i], e[i]));
        term = fminf(fmaxf(term, 1.0000000e-8f), 18.420680744f);
        bool v = ck[i] < (31 << 5);
        loss += v ? term : 0.0f;
        int c = v ? ck[i] : -1;
        bool up = c > best;
        best = up ? c : best;
        last = up ? term : last;
    }

    // ---- combine the two lanes of this race
    loss += __shfl_xor(loss, 1);
    int n = nloc + __shfl_xor(nloc, 1);
    int pbest = __shfl_xor(best, 1);
    float plast = __shfl_xor(last, 1);
    last = (pbest > best) ? plast : last;
    float th_loss = (live && n >= 2 && sub == 0) ? (loss - last) : 0.0f;
    int   th_cnt  = (live && n >= 2 && sub == 0) ? 1 : 0;

    // ---- block reduce
#pragma unroll
    for (int off = 32; off >= 1; off >>= 1) {
        th_loss += __shfl_down(th_loss, off);
        th_cnt  += __shfl_down(th_cnt, off);
    }
    if (lane == 0) { ls[wid] = th_loss; cs[wid] = th_cnt; }
    __syncthreads();
    if (t == 0) {
        float L = 0.0f; int C = 0;
#pragma unroll
        for (int w = 0; w < TPB / 64; ++w) { L += ls[w]; C += cs[w]; }
        partial_loss[blockIdx.x] = L;
        partial_cnt[blockIdx.x]  = C;
    }
}

__global__ __launch_bounds__(1024) void pl_final(const float* __restrict__ partial_loss,
                                                 const int* __restrict__ partial_cnt,
                                                 int nb, float* __restrict__ out) {
    float L = 0.0f;
    int C = 0;
    for (int i = threadIdx.x; i < nb; i += 1024) {
        L += partial_loss[i];
        C += partial_cnt[i];
    }
#pragma unroll
    for (int off = 32; off >= 1; off >>= 1) {
        L += __shfl_down(L, off);
        C += __shfl_down(C, off);
    }
    __shared__ float ls[1024 / 64];
    __shared__ int   cs[1024 / 64];
    int wid = threadIdx.x >> 6;
    int lane = threadIdx.x & 63;
    if (lane == 0) { ls[wid] = L; cs[wid] = C; }
    __syncthreads();
    if (threadIdx.x == 0) {
        float tl = 0.0f;
        int tc = 0;
#pragma unroll
        for (int w = 0; w < 1024 / 64; ++w) { tl += ls[w]; tc += cs[w]; }
        out[0] = (tc > 0) ? (tl / (float)tc) : 0.0f;
    }
}

extern "C" void kernel_launch(void* const* d_in, const int* in_sizes, int n_in,
                              void* d_out, int out_size, void* d_ws, size_t ws_size,
                              hipStream_t stream) {
    const float*         scores   = (const float*)d_in[0];
    const int*           rankings = (const int*)d_in[1];
    const unsigned char* mask     = (const unsigned char*)d_in[2];

    int B = in_sizes[0] / H;
    int nb = (B + RPB - 1) / RPB;  // 7813 blocks for B=1e6

    float* pl = (float*)d_ws;
    int*   pc = (int*)((char*)d_ws + (((size_t)nb * sizeof(float) + 255) & ~(size_t)255));

    pl_main<<<nb, TPB, 0, stream>>>(scores, rankings, mask, B, pl, pc);
    pl_final<<<1, 1024, 0, stream>>>(pl, pc, nb, (float*)d_out);
}

// Round 12
// 212.287 us; speedup vs baseline: 1.0120x; 1.0076x over previous
//
#include <hip/hip_runtime.h>
#include <stdint.h>

#define H 18
#define TPB 256
#define RPB 128                      // races per tile
#define GRID 512                     // persistent blocks (2 per CU)
#define ABYTES (RPB * H * 4)         // 9216 B per f32/i32 array per tile
#define BUFSZ (3 * ABYTES)           // 27648 B: scores | ranks | mask(worst)
#define SC_C (ABYTES / 16)           // 576 16B chunks per f32 array
#define CHUNK_SLOTS (3 * SC_C)       // 1728 chunk slots (fixed region bases)

__device__ __forceinline__ void gld16(const void* g, void* l) {
    __builtin_amdgcn_global_load_lds(
        (const __attribute__((address_space(1))) unsigned int*)g,
        (__attribute__((address_space(3))) unsigned int*)l, 16, 0, 0);
}

// R12: persistent blocks + LDS double-buffer + global_load_lds prefetch.
// issue(tile t+1) -> compute(tile t) -> __syncthreads() [vmcnt(0) drain].
// Loads for t+1 fly under compute of t: memory streams continuously.
__global__ __launch_bounds__(TPB) void pl_main(const float* __restrict__ scores,
                                               const int* __restrict__ rankings,
                                               const unsigned char* __restrict__ mask8,
                                               int B, int ntiles,
                                               float* __restrict__ partial_loss,
                                               int* __restrict__ partial_cnt) {
    __shared__ char sBuf[2 * BUFSZ];
    __shared__ int sFlag;
    __shared__ float ls[TPB / 64];
    __shared__ int   cs[TPB / 64];

    const int t = threadIdx.x;
    const int lane = t & 63;
    const int wid = t >> 6;

    // ---- mask dtype detect (proven R4-R11): int32 bools -> words 0/1;
    // u8-packed -> word>1 w.p.~1 in 256 words. Guard vs tiny buffers.
    if (t == 0) sFlag = 0;
    __syncthreads();
    {
        int nw = min(256, (B * H) / 4);   // u8 lower bound on buffer dwords
        if (t < nw) {
            unsigned int w = reinterpret_cast<const unsigned int*>(mask8)[t];
            if (__any(w > 1u) && lane == 0) atomicOr(&sFlag, 1);
        } else if (__any(false) && lane == 0) { }  // keep wave convergent
    }
    __syncthreads();
    const bool u8mode = (sFlag != 0);

    // ---- async stage of one tile into buf (raw bytes, linear LDS)
    auto issue = [&](int tile, int buf) {
        const int race0 = tile * RPB;
        const int limit = min(RPB, B - race0);
        const int abytes = limit * H * 4;          // f32/i32 array bytes
        const int scN = abytes >> 4;               // full 16B chunks
        const int mbytes = u8mode ? limit * H : abytes;
        const int mcN = mbytes >> 4;
        const char* sg = (const char*)scores + (size_t)race0 * H * 4;
        const char* rg = (const char*)rankings + (size_t)race0 * H * 4;
        const char* mg = (const char*)mask8 + (size_t)race0 * H * (u8mode ? 1 : 4);
        char* lb = sBuf + buf * BUFSZ;
#pragma unroll
        for (int k = 0; k < (CHUNK_SLOTS + TPB - 1) / TPB; ++k) {
            int c = k * TPB + t;
            if (c >= CHUNK_SLOTS) break;
            const char* g;
            bool act;
            if (c < SC_C)          { g = sg + (size_t)c * 16;              act = c < scN; }
            else if (c < 2 * SC_C) { g = rg + (size_t)(c - SC_C) * 16;     act = (c - SC_C) < scN; }
            else                   { g = mg + (size_t)(c - 2 * SC_C) * 16; act = (c - 2 * SC_C) < mcN; }
            if (act) gld16(g, lb + (size_t)c * 16);   // lane0 ptr = uniform base
        }
        // scalar remainders (plain load + ds_write; drained by next barrier)
        int rem = abytes - scN * 16;                  // 0 or 8 (limit odd)
        if (t * 4 < rem) {
            *(int*)(lb + scN * 16 + t * 4) =
                *(const int*)(sg + scN * 16 + t * 4);
            *(int*)(lb + ABYTES + scN * 16 + t * 4) =
                *(const int*)(rg + scN * 16 + t * 4);
            if (!u8mode)
                *(int*)(lb + 2 * ABYTES + scN * 16 + t * 4) =
                    *(const int*)(mg + scN * 16 + t * 4);
        }
        if (u8mode) {
            int mrem = mbytes - mcN * 16;             // 0..15
            if (t < mrem)
                *(lb + 2 * ABYTES + mcN * 16 + t) = *(mg + mcN * 16 + t);
        }
    };

    float th_loss = 0.0f;
    int th_cnt = 0;

    const int rb  = t >> 1;     // race within tile
    const int sub = t & 1;      // 9-horse half

    int tile = blockIdx.x;
    int cur = 0;
    if (tile < ntiles) issue(tile, 0);

    while (tile < ntiles) {
        __syncthreads();        // vmcnt(0) drain: buf[cur] resident; buf reuse safe
        int nxt = tile + GRID;
        if (nxt < ntiles) issue(nxt, cur ^ 1);   // flies under compute below

        const int limit = min(RPB, B - tile * RPB);
        const bool live = rb < limit;
        const char* lb = sBuf + cur * BUFSZ;
        const float* sF = (const float*)lb;
        const int*   rI = (const int*)(lb + ABYTES);
        const int*   mI = (const int*)(lb + 2 * ABYTES);
        const unsigned char* mU = (const unsigned char*)(lb + 2 * ABYTES);

        // ---- my 9 horses (R10 compute, consume-side transform)
        float s[9], e[9], run[9];
        int ck[9];
        int nloc = 0;
#pragma unroll
        for (int i = 0; i < 9; ++i) {
            int j = sub * 9 + i;
            int idx = rb * H + j;
            float fs = sF[idx];
            int rk = rI[idx];
            int mk = u8mode ? (int)mU[idx] : mI[idx];
            bool v = live && (mk != 0) && (rk >= 0);
            int key = v ? min(rk, 30) : 31;
            float scl = fminf(fmaxf(fs, -10.0f), 10.0f);
            s[i] = scl;
            ck[i] = (key << 5) | j;
            e[i] = v ? __expf(scl) : 0.0f;
            nloc += v ? 1 : 0;
        }

        // ---- run_i = sum over 18 horses b with ck_b >= ck_i of e_b
#pragma unroll
        for (int i = 0; i < 9; ++i) run[i] = e[i];
#pragma unroll
        for (int a = 0; a < 9; ++a) {
#pragma unroll
            for (int b = a + 1; b < 9; ++b) {
                bool cc = ck[b] > ck[a];
                run[a] += cc ? e[b] : 0.0f;
                run[b] += cc ? 0.0f : e[a];
            }
        }
#pragma unroll
        for (int p = 0; p < 9; ++p) {
            float pe = __shfl_xor(e[p], 1);
            int  pck = __shfl_xor(ck[p], 1);
#pragma unroll
            for (int i = 0; i < 9; ++i) {
                run[i] += (pck > ck[i]) ? pe : 0.0f;
            }
        }

        // ---- terms; last pick (max ck among valid) excluded; branchless
        float loss = 0.0f, last = 0.0f;
        int best = -1;
#pragma unroll
        for (int i = 0; i < 9; ++i) {
            float term = __logf(run[i]) - s[i];
            term = fminf(fmaxf(term, 1.0000000e-8f), 18.420680744f);
            bool v = ck[i] < (31 << 5);
            loss += v ? term : 0.0f;
            int c = v ? ck[i] : -1;
            bool up = c > best;
            best = up ? c : best;
            last = up ? term : last;
        }

        // ---- combine the race's two lanes; accumulate across tiles
        loss += __shfl_xor(loss, 1);
        int n = nloc + __shfl_xor(nloc, 1);
        int pbest = __shfl_xor(best, 1);
        float plast = __shfl_xor(last, 1);
        last = (pbest > best) ? plast : last;
        bool takes = live && (n >= 2) && (sub == 0);
        th_loss += takes ? (loss - last) : 0.0f;
        th_cnt  += takes ? 1 : 0;

        cur ^= 1;
        tile = nxt;
    }

    // ---- block reduce (once)
#pragma unroll
    for (int off = 32; off >= 1; off >>= 1) {
        th_loss += __shfl_down(th_loss, off);
        th_cnt  += __shfl_down(th_cnt, off);
    }
    if (lane == 0) { ls[wid] = th_loss; cs[wid] = th_cnt; }
    __syncthreads();
    if (t == 0) {
        float L = 0.0f; int C = 0;
#pragma unroll
        for (int w = 0; w < TPB / 64; ++w) { L += ls[w]; C += cs[w]; }
        partial_loss[blockIdx.x] = L;
        partial_cnt[blockIdx.x]  = C;
    }
}

__global__ __launch_bounds__(1024) void pl_final(const float* __restrict__ partial_loss,
                                                 const int* __restrict__ partial_cnt,
                                                 int nb, float* __restrict__ out) {
    float L = 0.0f;
    int C = 0;
    for (int i = threadIdx.x; i < nb; i += 1024) {
        L += partial_loss[i];
        C += partial_cnt[i];
    }
#pragma unroll
    for (int off = 32; off >= 1; off >>= 1) {
        L += __shfl_down(L, off);
        C += __shfl_down(C, off);
    }
    __shared__ float ls[1024 / 64];
    __shared__ int   cs[1024 / 64];
    int wid = threadIdx.x >> 6;
    int lane = threadIdx.x & 63;
    if (lane == 0) { ls[wid] = L; cs[wid] = C; }
    __syncthreads();
    if (threadIdx.x == 0) {
        float tl = 0.0f;
        int tc = 0;
#pragma unroll
        for (int w = 0; w < 1024 / 64; ++w) { tl += ls[w]; tc += cs[w]; }
        out[0] = (tc > 0) ? (tl / (float)tc) : 0.0f;
    }
}

extern "C" void kernel_launch(void* const* d_in, const int* in_sizes, int n_in,
                              void* d_out, int out_size, void* d_ws, size_t ws_size,
                              hipStream_t stream) {
    const float*         scores   = (const float*)d_in[0];
    const int*           rankings = (const int*)d_in[1];
    const unsigned char* mask     = (const unsigned char*)d_in[2];

    int B = in_sizes[0] / H;
    int ntiles = (B + RPB - 1) / RPB;       // 7813 for B=1e6
    int nb = min(GRID, ntiles);

    float* pl = (float*)d_ws;
    int*   pc = (int*)((char*)d_ws + (((size_t)GRID * sizeof(float) + 255) & ~(size_t)255));

    pl_main<<<nb, TPB, 0, stream>>>(scores, rankings, mask, B, ntiles, pl, pc);
    pl_final<<<1, 1024, 0, stream>>>(pl, pc, nb, (float*)d_out);
}